// Round 20
// baseline (235.162 us; speedup 1.0000x reference)
//
#include <hip/hip_runtime.h>
#include <hip/hip_bf16.h>
#include <cstdint>

#define DEV __device__ __forceinline__

using f32x4  = __attribute__((ext_vector_type(4))) float;
using bf16x8 = __attribute__((ext_vector_type(8))) __bf16;

static constexpr int D_    = 512;
static constexpr int ROWS  = 2048;
static constexpr int F_    = 2048;
static constexpr int NEXP  = 14;
static constexpr int NENT  = 3072;

#if defined(__has_builtin)
#if __has_builtin(__builtin_amdgcn_global_load_lds)
#define HAS_GLL 1
#endif
#endif

DEV unsigned short f2bf(float f) {
  unsigned int u = __builtin_bit_cast(unsigned int, f);
  unsigned int r = u + 0x7FFFu + ((u >> 16) & 1u);
  return (unsigned short)(r >> 16);
}
DEV unsigned int pack2(float a, float b) {
  return (unsigned int)f2bf(a) | ((unsigned int)f2bf(b) << 16);
}
DEV float gelu_tanh(float x) {
  float x3 = x * x * x;
  return 0.5f * x * (1.0f + tanhf(0.7978845608028654f * (x + 0.044715f * x3)));
}
DEV int prefix_base(const int* cnt, int e) {
  int base = 0;
  for (int i = 0; i < e; ++i) base += cnt[i];
  return base;
}

// ---------------- M=128 bf16-MFMA GEMM core (NT fp32 weights) ----------------
struct Shared128 { unsigned short As[128][72]; unsigned short Bs[64][72]; };

DEV void gemm128(const unsigned short* arow, const float* B, int ldb, int bcol0, int K,
                 f32x4 (&acc)[2][4], Shared128& sh)
{
  const int tid = threadIdx.x;
  const int lane = tid & 63, w = tid >> 6;
  const int ai = tid >> 1, ah = tid & 1;
  const int bj = tid >> 2, bq = tid & 3;
  for (int k0 = 0; k0 < K; k0 += 64) {
    __syncthreads();
    {
      const uint4* src = reinterpret_cast<const uint4*>(arow + k0 + ah * 32);
      uint4 v0 = src[0], v1 = src[1], v2 = src[2], v3 = src[3];
      uint4* dst = reinterpret_cast<uint4*>(&sh.As[ai][ah * 32]);
      dst[0] = v0; dst[1] = v1; dst[2] = v2; dst[3] = v3;
    }
    {
      const float4* src = reinterpret_cast<const float4*>(B + (size_t)(bcol0 + bj) * ldb + k0 + bq * 16);
      unsigned int pk[8];
      #pragma unroll
      for (int u = 0; u < 4; ++u) {
        float4 f = src[u];
        pk[u * 2]     = pack2(f.x, f.y);
        pk[u * 2 + 1] = pack2(f.z, f.w);
      }
      uint4* dst = reinterpret_cast<uint4*>(&sh.Bs[bj][bq * 16]);
      dst[0] = make_uint4(pk[0], pk[1], pk[2], pk[3]);
      dst[1] = make_uint4(pk[4], pk[5], pk[6], pk[7]);
    }
    __syncthreads();
    #pragma unroll
    for (int ks = 0; ks < 2; ++ks) {
      bf16x8 a[2], b[4];
      #pragma unroll
      for (int mi = 0; mi < 2; ++mi)
        a[mi] = *reinterpret_cast<const bf16x8*>(&sh.As[w * 32 + mi * 16 + (lane & 15)][ks * 32 + (lane >> 4) * 8]);
      #pragma unroll
      for (int ni = 0; ni < 4; ++ni)
        b[ni] = *reinterpret_cast<const bf16x8*>(&sh.Bs[ni * 16 + (lane & 15)][ks * 32 + (lane >> 4) * 8]);
      #pragma unroll
      for (int mi = 0; mi < 2; ++mi)
        #pragma unroll
        for (int ni = 0; ni < 4; ++ni)
          acc[mi][ni] = __builtin_amdgcn_mfma_f32_16x16x32_bf16(a[mi], b[ni], acc[mi][ni], 0, 0, 0);
    }
  }
}

// ---------------- M=64 x N=128 GEMM: packed-fragment B staged linearly via LDS ----------------
struct __align__(16) SharedMoE { unsigned short As[64][72]; unsigned short Bs[8192]; };  // 9.2 + 16 KB

DEV void gemm64x128L(const unsigned short* arow, const unsigned short* Bt,
                     f32x4 (&acc)[8], SharedMoE& sh)
{
  const int tid = threadIdx.x;
  const int lane = tid & 63, w = tid >> 6;
  const int ar = tid >> 2, aq = tid & 3;
  #pragma unroll
  for (int kt = 0; kt < 8; ++kt) {
    __syncthreads();
#ifdef HAS_GLL
    { // async stage B: wave w covers Bs[w*2048, +2048); 4 issues x (64 lanes x 16B = 512 shorts)
      const unsigned short* src = Bt + kt * 8192 + w * 2048 + lane * 8;
      unsigned short* dstBase = &sh.Bs[w * 2048];
      #pragma unroll
      for (int i = 0; i < 4; ++i)
        __builtin_amdgcn_global_load_lds(
            (const __attribute__((address_space(1))) unsigned int*)(src + i * 512),
            (__attribute__((address_space(3))) unsigned int*)(dstBase + i * 512),
            16, 0, 0);
    }
#else
    {
      const uint4* srcB = reinterpret_cast<const uint4*>(Bt + kt * 8192 + tid * 32);
      uint4 b0 = srcB[0], b1 = srcB[1], b2 = srcB[2], b3 = srcB[3];
      uint4* dstB = reinterpret_cast<uint4*>(&sh.Bs[tid * 32]);
      dstB[0] = b0; dstB[1] = b1; dstB[2] = b2; dstB[3] = b3;
    }
#endif
    { // stage A: 4 threads/row, 16 shorts (2x uint4) each -> 64x64
      const uint4* srcA = reinterpret_cast<const uint4*>(arow + kt * 64 + aq * 16);
      uint4 a0 = srcA[0], a1 = srcA[1];
      uint4* dstA = reinterpret_cast<uint4*>(&sh.As[ar][aq * 16]);
      dstA[0] = a0; dstA[1] = a1;
    }
    __syncthreads();
    bf16x8 a0 = *reinterpret_cast<const bf16x8*>(&sh.As[w * 16 + (lane & 15)][0 * 32 + (lane >> 4) * 8]);
    bf16x8 a1 = *reinterpret_cast<const bf16x8*>(&sh.As[w * 16 + (lane & 15)][1 * 32 + (lane >> 4) * 8]);
    #pragma unroll
    for (int ni = 0; ni < 8; ++ni) {
      bf16x8 b0 = *reinterpret_cast<const bf16x8*>(&sh.Bs[(ni * 2 + 0) * 512 + lane * 8]);
      bf16x8 b1 = *reinterpret_cast<const bf16x8*>(&sh.Bs[(ni * 2 + 1) * 512 + lane * 8]);
      acc[ni] = __builtin_amdgcn_mfma_f32_16x16x32_bf16(a0, b0, acc[ni], 0, 0, 0);
      acc[ni] = __builtin_amdgcn_mfma_f32_16x16x32_bf16(a1, b1, acc[ni], 0, 0, 0);
    }
  }
}

// ---------------- DIRECT pack body: global fragment-gather, no LDS, no barrier ----------------
DEV void pack_body(int pbid, int tid,
                   const float* w1A, const float* w1C, const float* w1B,
                   const float* w2A, const float* w2C, const float* w2B,
                   unsigned short* W1P, unsigned short* W2P)
{
  int bx = pbid & 127, z = pbid >> 7;
  const float* src;
  unsigned short* dstbase;
  int ld, ntile, ktile, KT;
  if (z < 14) {
    int e = z;
    src = e < 4 ? w1A + (size_t)e * D_ * F_ : e < 10 ? w1C + (size_t)(e - 4) * D_ * F_ : w1B + (size_t)(e - 10) * D_ * F_;
    dstbase = W1P + (size_t)e * F_ * D_;
    ld = F_; KT = 8;
    ntile = bx >> 3; ktile = bx & 7;
  } else {
    int e = z - 14;
    src = e < 4 ? w2A + (size_t)e * F_ * D_ : e < 10 ? w2C + (size_t)(e - 4) * F_ * D_ : w2B + (size_t)(e - 10) * F_ * D_;
    dstbase = W2P + (size_t)e * D_ * F_;
    ld = D_; KT = 32;
    ntile = bx >> 5; ktile = bx & 31;
  }
  int k0 = ktile * 64, n0 = ntile * 128;
  size_t tbase = (size_t)(ntile * KT + ktile) * 8192;
  float v[4][8];
  #pragma unroll
  for (int i = 0; i < 4; ++i) {
    int p = tid + 256 * i;
    int f = p >> 6, l = p & 63;
    int ks = f & 1, ni = f >> 1;
    int n = n0 + ni * 16 + (l & 15);
    int k = k0 + ks * 32 + ((l >> 4) << 3);
    const float* sp = src + (size_t)k * ld + n;
    #pragma unroll
    for (int j = 0; j < 8; ++j)
      v[i][j] = sp[(size_t)j * ld];
  }
  #pragma unroll
  for (int i = 0; i < 4; ++i) {
    int p = tid + 256 * i;
    unsigned int pk[4];
    #pragma unroll
    for (int j2 = 0; j2 < 4; ++j2)
      pk[j2] = pack2(v[i][2 * j2], v[i][2 * j2 + 1]);
    *reinterpret_cast<uint4*>(dstbase + tbase + (size_t)p * 8) = make_uint4(pk[0], pk[1], pk[2], pk[3]);
  }
}

// ---------------- LN1 (tokens -> x bf16) ----------------
__global__ __launch_bounds__(256) void k_ln(
    const float* tA, const float* tC, const float* tB,
    const float* g3, const float* b3, unsigned short* out)
{
  int r = blockIdx.x;
  int b = r >> 9, n = r & 511;
  int grp = n < 128 ? 0 : (n < 384 ? 1 : 2);
  const float* src = grp == 0 ? tA + (size_t)(b * 128 + n) * D_
                   : grp == 1 ? tC + (size_t)(b * 256 + n - 128) * D_
                              : tB + (size_t)(b * 128 + n - 384) * D_;
  int tid = threadIdx.x, lane = tid & 63, w = tid >> 6;
  float2 v = *reinterpret_cast<const float2*>(src + tid * 2);
  float s = v.x + v.y;
  float ss = v.x * v.x + v.y * v.y;
  #pragma unroll
  for (int off = 1; off < 64; off <<= 1) { s += __shfl_xor(s, off); ss += __shfl_xor(ss, off); }
  __shared__ float red[8];
  if (lane == 0) { red[w] = s; red[4 + w] = ss; }
  __syncthreads();
  float S  = red[0] + red[1] + red[2] + red[3];
  float SS = red[4] + red[5] + red[6] + red[7];
  float mean = S * (1.0f / 512.0f);
  float var  = SS * (1.0f / 512.0f) - mean * mean;
  float inv  = rsqrtf(var + 1e-5f);
  const float* gam = g3 + grp * D_;
  const float* bet = b3 + grp * D_;
  int d0 = tid * 2;
  out[(size_t)r * D_ + d0]     = f2bf((v.x - mean) * inv * gam[d0]     + bet[d0]);
  out[(size_t)r * D_ + d0 + 1] = f2bf((v.y - mean) * inv * gam[d0 + 1] + bet[d0 + 1]);
}

// ---------------- MERGED: QKV projection (384) + FULL direct weight pack (3584) ----------------
__global__ __launch_bounds__(256) void k_qkv_pack(
    const unsigned short* x, const float* Wqkv, const float* bqkv,
    unsigned short* Qg, unsigned short* Kg, unsigned short* Vg,
    const float* w1A, const float* w1C, const float* w1B,
    const float* w2A, const float* w2C, const float* w2B,
    unsigned short* W1P, unsigned short* W2P)
{
  __shared__ __align__(16) char smem[sizeof(Shared128)];
  int bid = blockIdx.x;
  int tid = threadIdx.x;
  if (bid < 384) {
    Shared128& sh = *reinterpret_cast<Shared128*>(smem);
    int bn = bid % 24, bm = (bid / 24) % 4, batch = bid / 96;
    int lane = tid & 63, w = tid >> 6;
    const unsigned short* arow = x + (size_t)(batch * 512 + bm * 128 + (tid >> 1)) * D_;
    f32x4 acc[2][4] = {};
    gemm128(arow, Wqkv, 512, bn * 64, 512, acc, sh);
    #pragma unroll
    for (int mi = 0; mi < 2; ++mi)
    #pragma unroll
    for (int ni = 0; ni < 4; ++ni)
    #pragma unroll
    for (int j = 0; j < 4; ++j) {
      int n = bm * 128 + w * 32 + mi * 16 + ((lane >> 4) << 2) + j;
      int col = bn * 64 + ni * 16 + (lane & 15);
      float val = acc[mi][ni][j] + bqkv[col];
      int part = col >> 9;
      int o = col & 511, h = o >> 6, d = o & 63;
      unsigned short* dst = part == 0 ? Qg : (part == 1 ? Kg : Vg);
      dst[(size_t)((batch * 8 + h) * 512 + n) * 64 + d] = f2bf(val);
    }
  } else {
    pack_body(bid - 384, tid, w1A, w1C, w1B, w2A, w2C, w2B, W1P, W2P);
  }
}

// ---------------- flash attention: 1 wave per block, 16 q-rows, no barriers ----------------
__global__ __launch_bounds__(64) void k_attn(const unsigned short* Qg, const unsigned short* Kg,
                                             const unsigned short* Vg, unsigned short* attn)
{
  __shared__ unsigned short Qs[16][72], Ks[64][72], VT[64][72], Ps[16][72];
  int qt16 = blockIdx.x, h = blockIdx.y, b = blockIdx.z;
  int lane = threadIdx.x;
  const unsigned short* Qb  = Qg + (size_t)((b * 8 + h) * 512) * 64;
  const unsigned short* Kbp = Kg + (size_t)((b * 8 + h) * 512) * 64;
  const unsigned short* Vbp = Vg + (size_t)((b * 8 + h) * 512) * 64;
  int q0 = qt16 * 16;
  {
    int row = lane >> 2, q4 = lane & 3;
    const uint4* src = reinterpret_cast<const uint4*>(Qb + (size_t)(q0 + row) * 64 + q4 * 16);
    uint4* dst = reinterpret_cast<uint4*>(&Qs[row][q4 * 16]);
    dst[0] = src[0]; dst[1] = src[1];
  }
  int nkt = qt16 < 8 ? 2 : (qt16 < 24 ? 6 : 8);   // A: keys A; C: keys A+C; B: all
  float mrun[4] = { -1e30f, -1e30f, -1e30f, -1e30f };
  float lrun[4] = {};
  f32x4 o[4] = {};
  for (int kt = 0; kt < nkt; ++kt) {
    #pragma unroll
    for (int it = 0; it < 4; ++it) {
      int row = it * 16 + (lane >> 2), q4 = lane & 3;
      const uint4* ksrc = reinterpret_cast<const uint4*>(Kbp + (size_t)(kt * 64 + row) * 64 + q4 * 16);
      uint4* kdst = reinterpret_cast<uint4*>(&Ks[row][q4 * 16]);
      kdst[0] = ksrc[0]; kdst[1] = ksrc[1];
      union { uint4 u; unsigned short s[8]; } vv0, vv1;
      const uint4* vsrc = reinterpret_cast<const uint4*>(Vbp + (size_t)(kt * 64 + row) * 64 + q4 * 16);
      vv0.u = vsrc[0]; vv1.u = vsrc[1];
      #pragma unroll
      for (int jj = 0; jj < 8; ++jj) {
        VT[q4 * 16 + jj][row]     = vv0.s[jj];
        VT[q4 * 16 + 8 + jj][row] = vv1.s[jj];
      }
    }
    f32x4 s[4] = {};
    #pragma unroll
    for (int ks = 0; ks < 2; ++ks) {
      bf16x8 aq = *reinterpret_cast<const bf16x8*>(&Qs[lane & 15][ks * 32 + (lane >> 4) * 8]);
      #pragma unroll
      for (int cc = 0; cc < 4; ++cc) {
        bf16x8 bk = *reinterpret_cast<const bf16x8*>(&Ks[cc * 16 + (lane & 15)][ks * 32 + (lane >> 4) * 8]);
        s[cc] = __builtin_amdgcn_mfma_f32_16x16x32_bf16(aq, bk, s[cc], 0, 0, 0);
      }
    }
    #pragma unroll
    for (int rr = 0; rr < 4; ++rr) {
      float s0 = s[0][rr] * 0.125f, s1 = s[1][rr] * 0.125f;
      float s2 = s[2][rr] * 0.125f, s3 = s[3][rr] * 0.125f;
      float mx = fmaxf(fmaxf(s0, s1), fmaxf(s2, s3));
      #pragma unroll
      for (int off = 1; off < 16; off <<= 1) mx = fmaxf(mx, __shfl_xor(mx, off));
      float mn = fmaxf(mrun[rr], mx);
      float al = expf(mrun[rr] - mn);
      mrun[rr] = mn;
      float p0 = expf(s0 - mn), p1 = expf(s1 - mn), p2 = expf(s2 - mn), p3 = expf(s3 - mn);
      float ps = p0 + p1 + p2 + p3;
      #pragma unroll
      for (int off = 1; off < 16; off <<= 1) ps += __shfl_xor(ps, off);
      lrun[rr] = lrun[rr] * al + ps;
      #pragma unroll
      for (int n4 = 0; n4 < 4; ++n4) o[n4][rr] *= al;
      int prow = ((lane >> 4) << 2) + rr;
      Ps[prow][0 * 16 + (lane & 15)] = f2bf(p0);
      Ps[prow][1 * 16 + (lane & 15)] = f2bf(p1);
      Ps[prow][2 * 16 + (lane & 15)] = f2bf(p2);
      Ps[prow][3 * 16 + (lane & 15)] = f2bf(p3);
    }
    #pragma unroll
    for (int ks = 0; ks < 2; ++ks) {
      bf16x8 ap = *reinterpret_cast<const bf16x8*>(&Ps[lane & 15][ks * 32 + (lane >> 4) * 8]);
      #pragma unroll
      for (int n4 = 0; n4 < 4; ++n4) {
        bf16x8 bv = *reinterpret_cast<const bf16x8*>(&VT[n4 * 16 + (lane & 15)][ks * 32 + (lane >> 4) * 8]);
        o[n4] = __builtin_amdgcn_mfma_f32_16x16x32_bf16(ap, bv, o[n4], 0, 0, 0);
      }
    }
  }
  #pragma unroll
  for (int n4 = 0; n4 < 4; ++n4)
  #pragma unroll
  for (int rr = 0; rr < 4; ++rr) {
    int qrow = q0 + ((lane >> 4) << 2) + rr;
    int col = h * 64 + n4 * 16 + (lane & 15);
    float val = o[n4][rr] / lrun[rr];
    attn[(size_t)(b * 512 + qrow) * 512 + col] = f2bf(val);
  }
}

// ---------------- output projection + residual (writes d_out = t) ----------------
__global__ __launch_bounds__(256) void k_wo(const unsigned short* attn, const float* Wo, const float* bo,
                                            const float* tokA, const float* tokC, const float* tokB,
                                            float* out)
{
  __shared__ Shared128 sh;
  int bid = blockIdx.x;
  int bn = bid & 7, bm = bid >> 3;
  int tid = threadIdx.x, lane = tid & 63, w = tid >> 6;
  const unsigned short* arow = attn + (size_t)(bm * 128 + (tid >> 1)) * D_;
  f32x4 acc[2][4] = {};
  gemm128(arow, Wo, 512, bn * 64, 512, acc, sh);
  #pragma unroll
  for (int mi = 0; mi < 2; ++mi)
  #pragma unroll
  for (int ni = 0; ni < 4; ++ni)
  #pragma unroll
  for (int j = 0; j < 4; ++j) {
    int row = bm * 128 + w * 32 + mi * 16 + ((lane >> 4) << 2) + j;
    int col = bn * 64 + ni * 16 + (lane & 15);
    float val = acc[mi][ni][j] + bo[col];
    int b = row >> 9, n = row & 511;
    float res;
    if (n < 128)      res = tokA[(size_t)(b * 128 + n) * D_ + col];
    else if (n < 384) res = tokC[(size_t)(b * 256 + n - 128) * D_ + col];
    else              res = tokB[(size_t)(b * 128 + n - 384) * D_ + col];
    out[(size_t)row * D_ + col] = res + val;
  }
}

// ---------------- router: fused all groups, fp32 LN2 + logits, emits nrm bf16 ----------------
__global__ __launch_bounds__(256) void k_router(const float* t,
    const float* ln2g, const float* ln2b,
    const float* WrA, const float* brA, const float* WrC, const float* brC,
    const float* WrB, const float* brB,
    int* cnt, int* tokexp, float* tokgate, unsigned short* nrm)
{
  int w = threadIdx.x >> 6, lane = threadIdx.x & 63;
  int r = blockIdx.x * 4 + w;
  int n = r & 511;
  int grp = n < 128 ? 0 : (n < 384 ? 1 : 2);
  int E = grp == 1 ? 6 : 4;
  int topk = grp == 1 ? 1 : 2;
  int egbase = grp == 0 ? 0 : (grp == 1 ? 4 : 10);
  const float* Wr = grp == 0 ? WrA : (grp == 1 ? WrC : WrB);
  const float* br = grp == 0 ? brA : (grp == 1 ? brC : brB);
  const float* tr = t + (size_t)r * D_;
  float xv[8];
  float s = 0.0f, ss = 0.0f;
  #pragma unroll
  for (int it = 0; it < 8; ++it) {
    float v = tr[it * 64 + lane];
    xv[it] = v; s += v; ss += v * v;
  }
  #pragma unroll
  for (int off = 1; off < 64; off <<= 1) { s += __shfl_xor(s, off); ss += __shfl_xor(ss, off); }
  float mean = s * (1.0f / 512.0f);
  float var  = ss * (1.0f / 512.0f) - mean * mean;
  float inv  = rsqrtf(var + 1e-5f);
  const float* gam = ln2g + grp * D_;
  const float* bet = ln2b + grp * D_;
  float acc[6] = {};
  #pragma unroll
  for (int it = 0; it < 8; ++it) {
    int d = it * 64 + lane;
    float nv = (xv[it] - mean) * inv * gam[d] + bet[d];
    nrm[(size_t)r * D_ + d] = f2bf(nv);
    #pragma unroll
    for (int e = 0; e < 6; ++e) if (e < E) acc[e] += nv * Wr[d * E + e];
  }
  #pragma unroll
  for (int e = 0; e < 6; ++e)
    #pragma unroll
    for (int off = 1; off < 64; off <<= 1) acc[e] += __shfl_xor(acc[e], off);
  if (lane == 0) {
    float p[6];
    float mx = -1e30f;
    #pragma unroll
    for (int e = 0; e < 6; ++e) if (e < E) { p[e] = acc[e] + br[e]; mx = fmaxf(mx, p[e]); }
    float sum = 0.0f;
    #pragma unroll
    for (int e = 0; e < 6; ++e) if (e < E) { p[e] = expf(p[e] - mx); sum += p[e]; }
    #pragma unroll
    for (int e = 0; e < 6; ++e) if (e < E) p[e] /= sum;
    int i1 = 0; float v1 = p[0];
    #pragma unroll
    for (int e = 1; e < 6; ++e) if (e < E && p[e] > v1) { v1 = p[e]; i1 = e; }
    if (topk == 1) {
      tokexp[r * 2]     = egbase + i1; tokgate[r * 2]     = 1.0f;
      tokexp[r * 2 + 1] = -1;          tokgate[r * 2 + 1] = 0.0f;
      atomicAdd(&cnt[egbase + i1], 1);
    } else {
      int i2 = -1; float v2 = -1e30f;
      #pragma unroll
      for (int e = 0; e < 6; ++e) if (e < E && e != i1 && p[e] > v2) { v2 = p[e]; i2 = e; }
      float tot = v1 + v2;
      tokexp[r * 2]     = egbase + i1; tokgate[r * 2]     = v1 / tot;
      tokexp[r * 2 + 1] = egbase + i2; tokgate[r * 2 + 1] = v2 / tot;
      atomicAdd(&cnt[egbase + i1], 1);
      atomicAdd(&cnt[egbase + i2], 1);
    }
  }
}

// ---------------- scatter into compact expert lists ----------------
__global__ __launch_bounds__(256) void k_scatter(const int* tokexp, const float* tokgate,
                                                 const int* cnt, int* cursor, int* list, float* gate)
{
  int r = blockIdx.x * 256 + threadIdx.x;
  #pragma unroll
  for (int j = 0; j < 2; ++j) {
    int e = tokexp[r * 2 + j];
    if (e >= 0) {
      int base = prefix_base(cnt, e);
      int s = atomicAdd(&cursor[e], 1);
      list[base + s] = r;
      gate[base + s] = tokgate[r * 2 + j];
    }
  }
}

// ---------------- MoE GEMM1 (64x128, XCD-swizzled 1-D grid, tt-fastest) ----------------
// logical lg = (b&7)*448 + (b>>3): consecutive logicals land on same XCD; the 16
// tt-blocks sharing one Bt are logically consecutive -> Bt L2-resident per XCD.
__global__ __launch_bounds__(256) void k_moe1(const unsigned short* nrm, const unsigned short* W1P,
    const float* b1A, const float* b1C, const float* b1B,
    const int* cnt, const int* list, unsigned short* H)
{
  int b = blockIdx.x;                      // 3584 = 8 * 448
  int lg = (b & 7) * 448 + (b >> 3);
  int e = lg >> 8;                         // 14 experts
  int rem = lg & 255;
  int ft = rem >> 4, tt = rem & 15;
  int c = cnt[e];
  if (tt * 64 >= c) return;
  __shared__ SharedMoE sh;
  const float* b1 = e < 4 ? b1A + (size_t)e * F_ : e < 10 ? b1C + (size_t)(e - 4) * F_ : b1B + (size_t)(e - 10) * F_;
  const unsigned short* Bt = W1P + (size_t)e * F_ * D_ + (size_t)(ft * 8) * 8192;
  int base = prefix_base(cnt, e);
  int tid = threadIdx.x, lane = tid & 63, w = tid >> 6;
  int ig = tt * 64 + (tid >> 2);
  int tok = list[base + (ig < c ? ig : c - 1)];
  const unsigned short* arow = nrm + (size_t)tok * D_;
  f32x4 acc[8] = {};
  gemm64x128L(arow, Bt, acc, sh);
  #pragma unroll
  for (int ni = 0; ni < 8; ++ni)
  #pragma unroll
  for (int j = 0; j < 4; ++j) {
    int rl = w * 16 + ((lane >> 4) << 2) + j;
    int sg = tt * 64 + rl;
    if (sg < c) {
      int col = ft * 128 + ni * 16 + (lane & 15);
      float val = acc[ni][j] + b1[col];
      H[(size_t)(base + sg) * F_ + col] = f2bf(gelu_tanh(val));
    }
  }
}

// ---------------- MoE GEMM2 (64x128, K-split x4, XCD-swizzled 1-D grid, tt-fastest) ----------------
__global__ __launch_bounds__(256) void k_moe2(const unsigned short* H, const unsigned short* W2P,
    const float* b2A, const float* b2C, const float* b2B,
    const int* cnt, const int* list, const float* gate, float* out)
{
  int b = blockIdx.x;                      // 3584 = 8 * 448
  int lg = (b & 7) * 448 + (b >> 3);
  int e = lg >> 8;
  int rem = lg & 255;
  int dt = rem >> 6, kc = (rem >> 4) & 3, tt = rem & 15;
  int c = cnt[e];
  if (tt * 64 >= c) return;
  __shared__ SharedMoE sh;
  const float* b2 = e < 4 ? b2A + (size_t)e * D_ : e < 10 ? b2C + (size_t)(e - 4) * D_ : b2B + (size_t)(e - 10) * D_;
  const unsigned short* Bt = W2P + (size_t)e * D_ * F_ + (size_t)(dt * 32 + kc * 8) * 8192;
  int base = prefix_base(cnt, e);
  int tid = threadIdx.x, lane = tid & 63, w = tid >> 6;
  int ig = tt * 64 + (tid >> 2);
  const unsigned short* arow = H + (size_t)(base + (ig < c ? ig : c - 1)) * F_ + kc * 512;
  f32x4 acc[8] = {};
  gemm64x128L(arow, Bt, acc, sh);
  #pragma unroll
  for (int ni = 0; ni < 8; ++ni)
  #pragma unroll
  for (int j = 0; j < 4; ++j) {
    int rl = w * 16 + ((lane >> 4) << 2) + j;
    int sg = tt * 64 + rl;
    if (sg < c) {
      int col = dt * 128 + ni * 16 + (lane & 15);
      float val = acc[ni][j] + (kc == 0 ? b2[col] : 0.0f);
      int tok = list[base + sg];
      atomicAdd(&out[(size_t)tok * D_ + col], gate[base + sg] * val);
    }
  }
}

extern "C" void kernel_launch(void* const* d_in, const int* in_sizes, int n_in,
                              void* d_out, int out_size, void* d_ws, size_t ws_size,
                              hipStream_t stream)
{
  const float* tokA = (const float*)d_in[0];
  const float* tokB = (const float*)d_in[1];
  const float* tokC = (const float*)d_in[2];
  const float* ln1g = (const float*)d_in[3];
  const float* ln1b = (const float*)d_in[4];
  const float* ln2g = (const float*)d_in[5];
  const float* ln2b = (const float*)d_in[6];
  const float* Wqkv = (const float*)d_in[7];
  const float* bqkv = (const float*)d_in[8];
  const float* Wo   = (const float*)d_in[9];
  const float* bo   = (const float*)d_in[10];
  const float* WrA  = (const float*)d_in[11];
  const float* brA  = (const float*)d_in[12];
  const float* W1A  = (const float*)d_in[13];
  const float* b1A  = (const float*)d_in[14];
  const float* W2A  = (const float*)d_in[15];
  const float* b2A  = (const float*)d_in[16];
  const float* WrC  = (const float*)d_in[17];
  const float* brC  = (const float*)d_in[18];
  const float* W1C  = (const float*)d_in[19];
  const float* b1C  = (const float*)d_in[20];
  const float* W2C  = (const float*)d_in[21];
  const float* b2C  = (const float*)d_in[22];
  const float* WrB  = (const float*)d_in[23];
  const float* brB  = (const float*)d_in[24];
  const float* W1B  = (const float*)d_in[25];
  const float* b1B  = (const float*)d_in[26];
  const float* W2B  = (const float*)d_in[27];
  const float* b2B  = (const float*)d_in[28];
  float* out = (float*)d_out;

  char* ws = (char*)d_ws;
  const size_t MB = 1024 * 1024;
  const size_t WSTRIDE = (size_t)NEXP * F_ * D_ * 2;   // 29,360,128
  unsigned short* xb   = (unsigned short*)(ws);        // LN1 out -> nrm (router out)
  unsigned short* nrm  = xb;
  unsigned short* Qg   = (unsigned short*)(ws + 2 * MB);
  unsigned short* Kg   = (unsigned short*)(ws + 4 * MB);
  unsigned short* Vg   = (unsigned short*)(ws + 6 * MB);
  unsigned short* attn = (unsigned short*)(ws + 8 * MB);
  unsigned short* W1P  = (unsigned short*)(ws + 16 * MB);
  unsigned short* W2P  = (unsigned short*)(ws + 16 * MB + WSTRIDE);
  unsigned short* H    = (unsigned short*)(ws + 16 * MB + 2 * WSTRIDE);
  char* small = ws + 16 * MB + 2 * WSTRIDE + (size_t)NENT * F_ * 2;
  int*   cnt     = (int*)(small);
  int*   cursor  = (int*)(small + 64);
  int*   tokexp  = (int*)(small + 256);
  float* tokgate = (float*)(small + 256 + ROWS * 2 * 4);
  int*   list    = (int*)(small + 256 + ROWS * 4 * 4);
  float* gate    = (float*)(small + 256 + ROWS * 4 * 4 + NENT * 4);

  hipMemsetAsync(cnt, 0, 128, stream);  // cnt + cursor
  k_ln<<<ROWS, 256, 0, stream>>>(tokA, tokC, tokB, ln1g, ln1b, xb);
  k_qkv_pack<<<384 + 3584, 256, 0, stream>>>(xb, Wqkv, bqkv, Qg, Kg, Vg,
                                             W1A, W1C, W1B, W2A, W2C, W2B, W1P, W2P);
  k_attn<<<dim3(32, 8, 4), 64, 0, stream>>>(Qg, Kg, Vg, attn);
  k_wo<<<128, 256, 0, stream>>>(attn, Wo, bo, tokA, tokC, tokB, out);
  k_router<<<512, 256, 0, stream>>>(out, ln2g, ln2b, WrA, brA, WrC, brC, WrB, brB,
                                    cnt, tokexp, tokgate, nrm);
  k_scatter<<<8, 256, 0, stream>>>(tokexp, tokgate, cnt, cursor, list, gate);
  k_moe1<<<3584, 256, 0, stream>>>(nrm, W1P, b1A, b1C, b1B, cnt, list, H);
  k_moe2<<<3584, 256, 0, stream>>>(H, W2P, b2A, b2C, b2B, cnt, list, gate, out);
}

// Round 21
// 206.922 us; speedup vs baseline: 1.1365x; 1.1365x over previous
//
#include <hip/hip_runtime.h>
#include <hip/hip_bf16.h>
#include <cstdint>

#define DEV __device__ __forceinline__

using f32x4  = __attribute__((ext_vector_type(4))) float;
using bf16x8 = __attribute__((ext_vector_type(8))) __bf16;

static constexpr int D_    = 512;
static constexpr int ROWS  = 2048;
static constexpr int F_    = 2048;
static constexpr int NEXP  = 14;
static constexpr int NENT  = 3072;

#if defined(__has_builtin)
#if __has_builtin(__builtin_amdgcn_global_load_lds)
#define HAS_GLL 1
#endif
#endif

DEV unsigned short f2bf(float f) {
  unsigned int u = __builtin_bit_cast(unsigned int, f);
  unsigned int r = u + 0x7FFFu + ((u >> 16) & 1u);
  return (unsigned short)(r >> 16);
}
DEV unsigned int pack2(float a, float b) {
  return (unsigned int)f2bf(a) | ((unsigned int)f2bf(b) << 16);
}
DEV float gelu_tanh(float x) {
  float x3 = x * x * x;
  return 0.5f * x * (1.0f + tanhf(0.7978845608028654f * (x + 0.044715f * x3)));
}
DEV int prefix_base(const int* cnt, int e) {
  int base = 0;
  for (int i = 0; i < e; ++i) base += cnt[i];
  return base;
}

// ---------------- M=128 bf16-MFMA GEMM core (NT fp32 weights) ----------------
struct Shared128 { unsigned short As[128][72]; unsigned short Bs[64][72]; };

DEV void gemm128(const unsigned short* arow, const float* B, int ldb, int bcol0, int K,
                 f32x4 (&acc)[2][4], Shared128& sh)
{
  const int tid = threadIdx.x;
  const int lane = tid & 63, w = tid >> 6;
  const int ai = tid >> 1, ah = tid & 1;
  const int bj = tid >> 2, bq = tid & 3;
  for (int k0 = 0; k0 < K; k0 += 64) {
    __syncthreads();
    {
      const uint4* src = reinterpret_cast<const uint4*>(arow + k0 + ah * 32);
      uint4 v0 = src[0], v1 = src[1], v2 = src[2], v3 = src[3];
      uint4* dst = reinterpret_cast<uint4*>(&sh.As[ai][ah * 32]);
      dst[0] = v0; dst[1] = v1; dst[2] = v2; dst[3] = v3;
    }
    {
      const float4* src = reinterpret_cast<const float4*>(B + (size_t)(bcol0 + bj) * ldb + k0 + bq * 16);
      unsigned int pk[8];
      #pragma unroll
      for (int u = 0; u < 4; ++u) {
        float4 f = src[u];
        pk[u * 2]     = pack2(f.x, f.y);
        pk[u * 2 + 1] = pack2(f.z, f.w);
      }
      uint4* dst = reinterpret_cast<uint4*>(&sh.Bs[bj][bq * 16]);
      dst[0] = make_uint4(pk[0], pk[1], pk[2], pk[3]);
      dst[1] = make_uint4(pk[4], pk[5], pk[6], pk[7]);
    }
    __syncthreads();
    #pragma unroll
    for (int ks = 0; ks < 2; ++ks) {
      bf16x8 a[2], b[4];
      #pragma unroll
      for (int mi = 0; mi < 2; ++mi)
        a[mi] = *reinterpret_cast<const bf16x8*>(&sh.As[w * 32 + mi * 16 + (lane & 15)][ks * 32 + (lane >> 4) * 8]);
      #pragma unroll
      for (int ni = 0; ni < 4; ++ni)
        b[ni] = *reinterpret_cast<const bf16x8*>(&sh.Bs[ni * 16 + (lane & 15)][ks * 32 + (lane >> 4) * 8]);
      #pragma unroll
      for (int mi = 0; mi < 2; ++mi)
        #pragma unroll
        for (int ni = 0; ni < 4; ++ni)
          acc[mi][ni] = __builtin_amdgcn_mfma_f32_16x16x32_bf16(a[mi], b[ni], acc[mi][ni], 0, 0, 0);
    }
  }
}

// ---------------- M=64 x N=128 GEMM: packed-fragment B staged linearly via LDS ----------------
struct __align__(16) SharedMoE { unsigned short As[64][72]; unsigned short Bs[8192]; };  // 9.2 + 16 KB

DEV void gemm64x128L(const unsigned short* arow, const unsigned short* Bt,
                     f32x4 (&acc)[8], SharedMoE& sh)
{
  const int tid = threadIdx.x;
  const int lane = tid & 63, w = tid >> 6;
  const int ar = tid >> 2, aq = tid & 3;
  #pragma unroll
  for (int kt = 0; kt < 8; ++kt) {
    __syncthreads();
#ifdef HAS_GLL
    { // async stage B: wave w covers Bs[w*2048, +2048); 4 issues x (64 lanes x 16B = 512 shorts)
      const unsigned short* src = Bt + kt * 8192 + w * 2048 + lane * 8;
      unsigned short* dstBase = &sh.Bs[w * 2048];
      #pragma unroll
      for (int i = 0; i < 4; ++i)
        __builtin_amdgcn_global_load_lds(
            (const __attribute__((address_space(1))) unsigned int*)(src + i * 512),
            (__attribute__((address_space(3))) unsigned int*)(dstBase + i * 512),
            16, 0, 0);
    }
#else
    {
      const uint4* srcB = reinterpret_cast<const uint4*>(Bt + kt * 8192 + tid * 32);
      uint4 b0 = srcB[0], b1 = srcB[1], b2 = srcB[2], b3 = srcB[3];
      uint4* dstB = reinterpret_cast<uint4*>(&sh.Bs[tid * 32]);
      dstB[0] = b0; dstB[1] = b1; dstB[2] = b2; dstB[3] = b3;
    }
#endif
    { // stage A: 4 threads/row, 16 shorts (2x uint4) each -> 64x64
      const uint4* srcA = reinterpret_cast<const uint4*>(arow + kt * 64 + aq * 16);
      uint4 a0 = srcA[0], a1 = srcA[1];
      uint4* dstA = reinterpret_cast<uint4*>(&sh.As[ar][aq * 16]);
      dstA[0] = a0; dstA[1] = a1;
    }
    __syncthreads();
    bf16x8 a0 = *reinterpret_cast<const bf16x8*>(&sh.As[w * 16 + (lane & 15)][0 * 32 + (lane >> 4) * 8]);
    bf16x8 a1 = *reinterpret_cast<const bf16x8*>(&sh.As[w * 16 + (lane & 15)][1 * 32 + (lane >> 4) * 8]);
    #pragma unroll
    for (int ni = 0; ni < 8; ++ni) {
      bf16x8 b0 = *reinterpret_cast<const bf16x8*>(&sh.Bs[(ni * 2 + 0) * 512 + lane * 8]);
      bf16x8 b1 = *reinterpret_cast<const bf16x8*>(&sh.Bs[(ni * 2 + 1) * 512 + lane * 8]);
      acc[ni] = __builtin_amdgcn_mfma_f32_16x16x32_bf16(a0, b0, acc[ni], 0, 0, 0);
      acc[ni] = __builtin_amdgcn_mfma_f32_16x16x32_bf16(a1, b1, acc[ni], 0, 0, 0);
    }
  }
}

// ---------------- shared pack body: one 64K x 128N tile -> fragment order ----------------
// pbid in [0, 3584): z = pbid >> 7 (28), bx = pbid & 127.
DEV void pack_body(int pbid, int tid, unsigned short (*sh)[138],
                   const float* w1A, const float* w1C, const float* w1B,
                   const float* w2A, const float* w2C, const float* w2B,
                   unsigned short* W1P, unsigned short* W2P)
{
  int bx = pbid & 127, z = pbid >> 7;
  const float* src;
  unsigned short* dstbase;
  int ld, ntile, ktile, KT;
  if (z < 14) {
    int e = z;
    src = e < 4 ? w1A + (size_t)e * D_ * F_ : e < 10 ? w1C + (size_t)(e - 4) * D_ * F_ : w1B + (size_t)(e - 10) * D_ * F_;
    dstbase = W1P + (size_t)e * F_ * D_;
    ld = F_; KT = 8;
    ntile = bx >> 3; ktile = bx & 7;       // N=2048: 16 ntiles, K=512: 8 ktiles
  } else {
    int e = z - 14;
    src = e < 4 ? w2A + (size_t)e * F_ * D_ : e < 10 ? w2C + (size_t)(e - 4) * F_ * D_ : w2B + (size_t)(e - 10) * F_ * D_;
    dstbase = W2P + (size_t)e * D_ * F_;
    ld = D_; KT = 32;
    ntile = bx >> 5; ktile = bx & 31;      // N=512: 4 ntiles, K=2048: 32 ktiles
  }
  int k0 = ktile * 64, n0 = ntile * 128;
  {
    int r = tid >> 2, q = tid & 3;         // 4 threads/row, 32 floats each (32 KB total)
    const float4* sp = reinterpret_cast<const float4*>(src + (size_t)(k0 + r) * ld + n0 + q * 32);
    unsigned int* shw = reinterpret_cast<unsigned int*>(&sh[r][q * 32]);
    #pragma unroll
    for (int u = 0; u < 8; ++u) {
      float4 v = sp[u];
      shw[u * 2]     = pack2(v.x, v.y);
      shw[u * 2 + 1] = pack2(v.z, v.w);
    }
  }
  __syncthreads();
  size_t tbase = (size_t)(ntile * KT + ktile) * 8192;
  #pragma unroll
  for (int i = 0; i < 4; ++i) {
    int p = tid + 256 * i;
    int f = p >> 6, l = p & 63;
    int ks = f & 1, ni = f >> 1;
    int nl = ni * 16 + (l & 15);
    int kl = ks * 32 + (l >> 4) * 8;
    unsigned short tmp[8];
    #pragma unroll
    for (int j = 0; j < 8; ++j) tmp[j] = sh[kl + j][nl];
    *reinterpret_cast<uint4*>(dstbase + tbase + (size_t)p * 8) = *reinterpret_cast<const uint4*>(tmp);
  }
}

// ---------------- LN1 (tokens -> x bf16) ----------------
__global__ __launch_bounds__(256) void k_ln(
    const float* tA, const float* tC, const float* tB,
    const float* g3, const float* b3, unsigned short* out)
{
  int r = blockIdx.x;
  int b = r >> 9, n = r & 511;
  int grp = n < 128 ? 0 : (n < 384 ? 1 : 2);
  const float* src = grp == 0 ? tA + (size_t)(b * 128 + n) * D_
                   : grp == 1 ? tC + (size_t)(b * 256 + n - 128) * D_
                              : tB + (size_t)(b * 128 + n - 384) * D_;
  int tid = threadIdx.x, lane = tid & 63, w = tid >> 6;
  float2 v = *reinterpret_cast<const float2*>(src + tid * 2);
  float s = v.x + v.y;
  float ss = v.x * v.x + v.y * v.y;
  #pragma unroll
  for (int off = 1; off < 64; off <<= 1) { s += __shfl_xor(s, off); ss += __shfl_xor(ss, off); }
  __shared__ float red[8];
  if (lane == 0) { red[w] = s; red[4 + w] = ss; }
  __syncthreads();
  float S  = red[0] + red[1] + red[2] + red[3];
  float SS = red[4] + red[5] + red[6] + red[7];
  float mean = S * (1.0f / 512.0f);
  float var  = SS * (1.0f / 512.0f) - mean * mean;
  float inv  = rsqrtf(var + 1e-5f);
  const float* gam = g3 + grp * D_;
  const float* bet = b3 + grp * D_;
  int d0 = tid * 2;
  out[(size_t)r * D_ + d0]     = f2bf((v.x - mean) * inv * gam[d0]     + bet[d0]);
  out[(size_t)r * D_ + d0 + 1] = f2bf((v.y - mean) * inv * gam[d0 + 1] + bet[d0 + 1]);
}

// ---------------- FUSED: QKV projection (384) + pack part 1 (1200) ----------------
__global__ __launch_bounds__(256) void k_qkv_pack(
    const unsigned short* x, const float* Wqkv, const float* bqkv,
    unsigned short* Qg, unsigned short* Kg, unsigned short* Vg,
    const float* w1A, const float* w1C, const float* w1B,
    const float* w2A, const float* w2C, const float* w2B,
    unsigned short* W1P, unsigned short* W2P)
{
  __shared__ __align__(16) char smem[sizeof(Shared128)];
  int bid = blockIdx.x;
  int tid = threadIdx.x;
  if (bid < 384) {
    Shared128& sh = *reinterpret_cast<Shared128*>(smem);
    int bn = bid % 24, bm = (bid / 24) % 4, batch = bid / 96;
    int lane = tid & 63, w = tid >> 6;
    const unsigned short* arow = x + (size_t)(batch * 512 + bm * 128 + (tid >> 1)) * D_;
    f32x4 acc[2][4] = {};
    gemm128(arow, Wqkv, 512, bn * 64, 512, acc, sh);
    #pragma unroll
    for (int mi = 0; mi < 2; ++mi)
    #pragma unroll
    for (int ni = 0; ni < 4; ++ni)
    #pragma unroll
    for (int j = 0; j < 4; ++j) {
      int n = bm * 128 + w * 32 + mi * 16 + ((lane >> 4) << 2) + j;
      int col = bn * 64 + ni * 16 + (lane & 15);
      float val = acc[mi][ni][j] + bqkv[col];
      int part = col >> 9;
      int o = col & 511, h = o >> 6, d = o & 63;
      unsigned short* dst = part == 0 ? Qg : (part == 1 ? Kg : Vg);
      dst[(size_t)((batch * 8 + h) * 512 + n) * 64 + d] = f2bf(val);
    }
  } else {
    pack_body(bid - 384, tid, reinterpret_cast<unsigned short (*)[138]>(smem),
              w1A, w1C, w1B, w2A, w2C, w2B, W1P, W2P);
  }
}

// ---------------- flash attention: 1 wave per block, 16 q-rows, no barriers ----------------
__global__ __launch_bounds__(64) void k_attn(const unsigned short* Qg, const unsigned short* Kg,
                                             const unsigned short* Vg, unsigned short* attn)
{
  __shared__ unsigned short Qs[16][72], Ks[64][72], VT[64][72], Ps[16][72];
  int qt16 = blockIdx.x, h = blockIdx.y, b = blockIdx.z;
  int lane = threadIdx.x;
  const unsigned short* Qb  = Qg + (size_t)((b * 8 + h) * 512) * 64;
  const unsigned short* Kbp = Kg + (size_t)((b * 8 + h) * 512) * 64;
  const unsigned short* Vbp = Vg + (size_t)((b * 8 + h) * 512) * 64;
  int q0 = qt16 * 16;
  {
    int row = lane >> 2, q4 = lane & 3;
    const uint4* src = reinterpret_cast<const uint4*>(Qb + (size_t)(q0 + row) * 64 + q4 * 16);
    uint4* dst = reinterpret_cast<uint4*>(&Qs[row][q4 * 16]);
    dst[0] = src[0]; dst[1] = src[1];
  }
  int nkt = qt16 < 8 ? 2 : (qt16 < 24 ? 6 : 8);   // A: keys A; C: keys A+C; B: all
  float mrun[4] = { -1e30f, -1e30f, -1e30f, -1e30f };
  float lrun[4] = {};
  f32x4 o[4] = {};
  for (int kt = 0; kt < nkt; ++kt) {
    #pragma unroll
    for (int it = 0; it < 4; ++it) {
      int row = it * 16 + (lane >> 2), q4 = lane & 3;
      const uint4* ksrc = reinterpret_cast<const uint4*>(Kbp + (size_t)(kt * 64 + row) * 64 + q4 * 16);
      uint4* kdst = reinterpret_cast<uint4*>(&Ks[row][q4 * 16]);
      kdst[0] = ksrc[0]; kdst[1] = ksrc[1];
      union { uint4 u; unsigned short s[8]; } vv0, vv1;
      const uint4* vsrc = reinterpret_cast<const uint4*>(Vbp + (size_t)(kt * 64 + row) * 64 + q4 * 16);
      vv0.u = vsrc[0]; vv1.u = vsrc[1];
      #pragma unroll
      for (int jj = 0; jj < 8; ++jj) {
        VT[q4 * 16 + jj][row]     = vv0.s[jj];
        VT[q4 * 16 + 8 + jj][row] = vv1.s[jj];
      }
    }
    f32x4 s[4] = {};
    #pragma unroll
    for (int ks = 0; ks < 2; ++ks) {
      bf16x8 aq = *reinterpret_cast<const bf16x8*>(&Qs[lane & 15][ks * 32 + (lane >> 4) * 8]);
      #pragma unroll
      for (int cc = 0; cc < 4; ++cc) {
        bf16x8 bk = *reinterpret_cast<const bf16x8*>(&Ks[cc * 16 + (lane & 15)][ks * 32 + (lane >> 4) * 8]);
        s[cc] = __builtin_amdgcn_mfma_f32_16x16x32_bf16(aq, bk, s[cc], 0, 0, 0);
      }
    }
    #pragma unroll
    for (int rr = 0; rr < 4; ++rr) {
      float s0 = s[0][rr] * 0.125f, s1 = s[1][rr] * 0.125f;
      float s2 = s[2][rr] * 0.125f, s3 = s[3][rr] * 0.125f;
      float mx = fmaxf(fmaxf(s0, s1), fmaxf(s2, s3));
      #pragma unroll
      for (int off = 1; off < 16; off <<= 1) mx = fmaxf(mx, __shfl_xor(mx, off));
      float mn = fmaxf(mrun[rr], mx);
      float al = expf(mrun[rr] - mn);
      mrun[rr] = mn;
      float p0 = expf(s0 - mn), p1 = expf(s1 - mn), p2 = expf(s2 - mn), p3 = expf(s3 - mn);
      float ps = p0 + p1 + p2 + p3;
      #pragma unroll
      for (int off = 1; off < 16; off <<= 1) ps += __shfl_xor(ps, off);
      lrun[rr] = lrun[rr] * al + ps;
      #pragma unroll
      for (int n4 = 0; n4 < 4; ++n4) o[n4][rr] *= al;
      int prow = ((lane >> 4) << 2) + rr;
      Ps[prow][0 * 16 + (lane & 15)] = f2bf(p0);
      Ps[prow][1 * 16 + (lane & 15)] = f2bf(p1);
      Ps[prow][2 * 16 + (lane & 15)] = f2bf(p2);
      Ps[prow][3 * 16 + (lane & 15)] = f2bf(p3);
    }
    #pragma unroll
    for (int ks = 0; ks < 2; ++ks) {
      bf16x8 ap = *reinterpret_cast<const bf16x8*>(&Ps[lane & 15][ks * 32 + (lane >> 4) * 8]);
      #pragma unroll
      for (int n4 = 0; n4 < 4; ++n4) {
        bf16x8 bv = *reinterpret_cast<const bf16x8*>(&VT[n4 * 16 + (lane & 15)][ks * 32 + (lane >> 4) * 8]);
        o[n4] = __builtin_amdgcn_mfma_f32_16x16x32_bf16(ap, bv, o[n4], 0, 0, 0);
      }
    }
  }
  #pragma unroll
  for (int n4 = 0; n4 < 4; ++n4)
  #pragma unroll
  for (int rr = 0; rr < 4; ++rr) {
    int qrow = q0 + ((lane >> 4) << 2) + rr;
    int col = h * 64 + n4 * 16 + (lane & 15);
    float val = o[n4][rr] / lrun[rr];
    attn[(size_t)(b * 512 + qrow) * 512 + col] = f2bf(val);
  }
}

// ---------------- FUSED: Wo projection + residual (128) + pack part 2 (1200) ----------------
__global__ __launch_bounds__(256) void k_wo_pack(
    const unsigned short* attn, const float* Wo, const float* bo,
    const float* tokA, const float* tokC, const float* tokB, float* out,
    const float* w1A, const float* w1C, const float* w1B,
    const float* w2A, const float* w2C, const float* w2B,
    unsigned short* W1P, unsigned short* W2P)
{
  __shared__ __align__(16) char smem[sizeof(Shared128)];
  int bid = blockIdx.x;
  int tid = threadIdx.x;
  if (bid < 128) {
    Shared128& sh = *reinterpret_cast<Shared128*>(smem);
    int bn = bid & 7, bm = bid >> 3;
    int lane = tid & 63, w = tid >> 6;
    const unsigned short* arow = attn + (size_t)(bm * 128 + (tid >> 1)) * D_;
    f32x4 acc[2][4] = {};
    gemm128(arow, Wo, 512, bn * 64, 512, acc, sh);
    #pragma unroll
    for (int mi = 0; mi < 2; ++mi)
    #pragma unroll
    for (int ni = 0; ni < 4; ++ni)
    #pragma unroll
    for (int j = 0; j < 4; ++j) {
      int row = bm * 128 + w * 32 + mi * 16 + ((lane >> 4) << 2) + j;
      int col = bn * 64 + ni * 16 + (lane & 15);
      float val = acc[mi][ni][j] + bo[col];
      int b = row >> 9, n = row & 511;
      float res;
      if (n < 128)      res = tokA[(size_t)(b * 128 + n) * D_ + col];
      else if (n < 384) res = tokC[(size_t)(b * 256 + n - 128) * D_ + col];
      else              res = tokB[(size_t)(b * 128 + n - 384) * D_ + col];
      out[(size_t)row * D_ + col] = res + val;
    }
  } else {
    pack_body(1200 + bid - 128, tid, reinterpret_cast<unsigned short (*)[138]>(smem),
              w1A, w1C, w1B, w2A, w2C, w2B, W1P, W2P);
  }
}

// ---------------- FUSED: router (512) + pack part 3 (1184) ----------------
__global__ __launch_bounds__(256) void k_router_pack(const float* t,
    const float* ln2g, const float* ln2b,
    const float* WrA, const float* brA, const float* WrC, const float* brC,
    const float* WrB, const float* brB,
    int* cnt, int* tokexp, float* tokgate, unsigned short* nrm,
    const float* w1A, const float* w1C, const float* w1B,
    const float* w2A, const float* w2C, const float* w2B,
    unsigned short* W1P, unsigned short* W2P)
{
  __shared__ __align__(16) char smem[64 * 138 * 2];
  int bid = blockIdx.x;
  if (bid >= 512) {
    pack_body(2400 + bid - 512, threadIdx.x, reinterpret_cast<unsigned short (*)[138]>(smem),
              w1A, w1C, w1B, w2A, w2C, w2B, W1P, W2P);
    return;
  }
  int w = threadIdx.x >> 6, lane = threadIdx.x & 63;
  int r = bid * 4 + w;
  int n = r & 511;
  int grp = n < 128 ? 0 : (n < 384 ? 1 : 2);
  int E = grp == 1 ? 6 : 4;
  int topk = grp == 1 ? 1 : 2;
  int egbase = grp == 0 ? 0 : (grp == 1 ? 4 : 10);
  const float* Wr = grp == 0 ? WrA : (grp == 1 ? WrC : WrB);
  const float* br = grp == 0 ? brA : (grp == 1 ? brC : brB);
  const float* tr = t + (size_t)r * D_;
  float xv[8];
  float s = 0.0f, ss = 0.0f;
  #pragma unroll
  for (int it = 0; it < 8; ++it) {
    float v = tr[it * 64 + lane];
    xv[it] = v; s += v; ss += v * v;
  }
  #pragma unroll
  for (int off = 1; off < 64; off <<= 1) { s += __shfl_xor(s, off); ss += __shfl_xor(ss, off); }
  float mean = s * (1.0f / 512.0f);
  float var  = ss * (1.0f / 512.0f) - mean * mean;
  float inv  = rsqrtf(var + 1e-5f);
  const float* gam = ln2g + grp * D_;
  const float* bet = ln2b + grp * D_;
  float acc[6] = {};
  #pragma unroll
  for (int it = 0; it < 8; ++it) {
    int d = it * 64 + lane;
    float nv = (xv[it] - mean) * inv * gam[d] + bet[d];
    nrm[(size_t)r * D_ + d] = f2bf(nv);
    #pragma unroll
    for (int e = 0; e < 6; ++e) if (e < E) acc[e] += nv * Wr[d * E + e];
  }
  #pragma unroll
  for (int e = 0; e < 6; ++e)
    #pragma unroll
    for (int off = 1; off < 64; off <<= 1) acc[e] += __shfl_xor(acc[e], off);
  if (lane == 0) {
    float p[6];
    float mx = -1e30f;
    #pragma unroll
    for (int e = 0; e < 6; ++e) if (e < E) { p[e] = acc[e] + br[e]; mx = fmaxf(mx, p[e]); }
    float sum = 0.0f;
    #pragma unroll
    for (int e = 0; e < 6; ++e) if (e < E) { p[e] = expf(p[e] - mx); sum += p[e]; }
    #pragma unroll
    for (int e = 0; e < 6; ++e) if (e < E) p[e] /= sum;
    int i1 = 0; float v1 = p[0];
    #pragma unroll
    for (int e = 1; e < 6; ++e) if (e < E && p[e] > v1) { v1 = p[e]; i1 = e; }
    if (topk == 1) {
      tokexp[r * 2]     = egbase + i1; tokgate[r * 2]     = 1.0f;
      tokexp[r * 2 + 1] = -1;          tokgate[r * 2 + 1] = 0.0f;
      atomicAdd(&cnt[egbase + i1], 1);
    } else {
      int i2 = -1; float v2 = -1e30f;
      #pragma unroll
      for (int e = 0; e < 6; ++e) if (e < E && e != i1 && p[e] > v2) { v2 = p[e]; i2 = e; }
      float tot = v1 + v2;
      tokexp[r * 2]     = egbase + i1; tokgate[r * 2]     = v1 / tot;
      tokexp[r * 2 + 1] = egbase + i2; tokgate[r * 2 + 1] = v2 / tot;
      atomicAdd(&cnt[egbase + i1], 1);
      atomicAdd(&cnt[egbase + i2], 1);
    }
  }
}

// ---------------- scatter into compact expert lists (prefix computed inline) ----------------
__global__ __launch_bounds__(256) void k_scatter(const int* tokexp, const float* tokgate,
                                                 const int* cnt, int* cursor, int* list, float* gate)
{
  int r = blockIdx.x * 256 + threadIdx.x;
  #pragma unroll
  for (int j = 0; j < 2; ++j) {
    int e = tokexp[r * 2 + j];
    if (e >= 0) {
      int base = prefix_base(cnt, e);
      int s = atomicAdd(&cursor[e], 1);
      list[base + s] = r;
      gate[base + s] = tokgate[r * 2 + j];
    }
  }
}

// ---------------- MoE GEMM1 (64x128, packed B via LDS): H = gelu(gather(nrm) @ W1^T + b1) ----------------
__global__ __launch_bounds__(256) void k_moe1(const unsigned short* nrm, const unsigned short* W1P,
    const float* b1A, const float* b1C, const float* b1B,
    const int* cnt, const int* list, unsigned short* H)
{
  int ft = blockIdx.x, tt = blockIdx.y, e = blockIdx.z;
  int c = cnt[e];
  if (tt * 64 >= c) return;
  __shared__ SharedMoE sh;
  const float* b1 = e < 4 ? b1A + (size_t)e * F_ : e < 10 ? b1C + (size_t)(e - 4) * F_ : b1B + (size_t)(e - 10) * F_;
  const unsigned short* Bt = W1P + (size_t)e * F_ * D_ + (size_t)(ft * 8) * 8192;
  int base = prefix_base(cnt, e);
  int tid = threadIdx.x, lane = tid & 63, w = tid >> 6;
  int ig = tt * 64 + (tid >> 2);
  int tok = list[base + (ig < c ? ig : c - 1)];
  const unsigned short* arow = nrm + (size_t)tok * D_;
  f32x4 acc[8] = {};
  gemm64x128L(arow, Bt, acc, sh);
  #pragma unroll
  for (int ni = 0; ni < 8; ++ni)
  #pragma unroll
  for (int j = 0; j < 4; ++j) {
    int rl = w * 16 + ((lane >> 4) << 2) + j;
    int sg = tt * 64 + rl;
    if (sg < c) {
      int col = ft * 128 + ni * 16 + (lane & 15);
      float val = acc[ni][j] + b1[col];
      H[(size_t)(base + sg) * F_ + col] = f2bf(gelu_tanh(val));
    }
  }
}

// ---------------- MoE GEMM2 (64x128, packed B via LDS, K-split x4): out += gate*(H @ W2^T + b2@kc0) ----------------
__global__ __launch_bounds__(256) void k_moe2(const unsigned short* H, const unsigned short* W2P,
    const float* b2A, const float* b2C, const float* b2B,
    const int* cnt, const int* list, const float* gate, float* out)
{
  int dt = blockIdx.x, tt = blockIdx.y >> 2, kc = blockIdx.y & 3, e = blockIdx.z;
  int c = cnt[e];
  if (tt * 64 >= c) return;
  __shared__ SharedMoE sh;
  const float* b2 = e < 4 ? b2A + (size_t)e * D_ : e < 10 ? b2C + (size_t)(e - 4) * D_ : b2B + (size_t)(e - 10) * D_;
  const unsigned short* Bt = W2P + (size_t)e * D_ * F_ + (size_t)(dt * 32 + kc * 8) * 8192;
  int base = prefix_base(cnt, e);
  int tid = threadIdx.x, lane = tid & 63, w = tid >> 6;
  int ig = tt * 64 + (tid >> 2);
  const unsigned short* arow = H + (size_t)(base + (ig < c ? ig : c - 1)) * F_ + kc * 512;
  f32x4 acc[8] = {};
  gemm64x128L(arow, Bt, acc, sh);
  #pragma unroll
  for (int ni = 0; ni < 8; ++ni)
  #pragma unroll
  for (int j = 0; j < 4; ++j) {
    int rl = w * 16 + ((lane >> 4) << 2) + j;
    int sg = tt * 64 + rl;
    if (sg < c) {
      int col = dt * 128 + ni * 16 + (lane & 15);
      float val = acc[ni][j] + (kc == 0 ? b2[col] : 0.0f);
      int tok = list[base + sg];
      atomicAdd(&out[(size_t)tok * D_ + col], gate[base + sg] * val);
    }
  }
}

extern "C" void kernel_launch(void* const* d_in, const int* in_sizes, int n_in,
                              void* d_out, int out_size, void* d_ws, size_t ws_size,
                              hipStream_t stream)
{
  const float* tokA = (const float*)d_in[0];
  const float* tokB = (const float*)d_in[1];
  const float* tokC = (const float*)d_in[2];
  const float* ln1g = (const float*)d_in[3];
  const float* ln1b = (const float*)d_in[4];
  const float* ln2g = (const float*)d_in[5];
  const float* ln2b = (const float*)d_in[6];
  const float* Wqkv = (const float*)d_in[7];
  const float* bqkv = (const float*)d_in[8];
  const float* Wo   = (const float*)d_in[9];
  const float* bo   = (const float*)d_in[10];
  const float* WrA  = (const float*)d_in[11];
  const float* brA  = (const float*)d_in[12];
  const float* W1A  = (const float*)d_in[13];
  const float* b1A  = (const float*)d_in[14];
  const float* W2A  = (const float*)d_in[15];
  const float* b2A  = (const float*)d_in[16];
  const float* WrC  = (const float*)d_in[17];
  const float* brC  = (const float*)d_in[18];
  const float* W1C  = (const float*)d_in[19];
  const float* b1C  = (const float*)d_in[20];
  const float* W2C  = (const float*)d_in[21];
  const float* b2C  = (const float*)d_in[22];
  const float* WrB  = (const float*)d_in[23];
  const float* brB  = (const float*)d_in[24];
  const float* W1B  = (const float*)d_in[25];
  const float* b1B  = (const float*)d_in[26];
  const float* W2B  = (const float*)d_in[27];
  const float* b2B  = (const float*)d_in[28];
  float* out = (float*)d_out;

  char* ws = (char*)d_ws;
  const size_t MB = 1024 * 1024;
  const size_t WSTRIDE = (size_t)NEXP * F_ * D_ * 2;   // 29,360,128
  unsigned short* xb   = (unsigned short*)(ws);        // LN1 out -> nrm (router out)
  unsigned short* nrm  = xb;
  unsigned short* Qg   = (unsigned short*)(ws + 2 * MB);
  unsigned short* Kg   = (unsigned short*)(ws + 4 * MB);
  unsigned short* Vg   = (unsigned short*)(ws + 6 * MB);
  unsigned short* attn = (unsigned short*)(ws + 8 * MB);
  unsigned short* W1P  = (unsigned short*)(ws + 16 * MB);
  unsigned short* W2P  = (unsigned short*)(ws + 16 * MB + WSTRIDE);
  unsigned short* H    = (unsigned short*)(ws + 16 * MB + 2 * WSTRIDE);
  char* small = ws + 16 * MB + 2 * WSTRIDE + (size_t)NENT * F_ * 2;
  int*   cnt     = (int*)(small);
  int*   cursor  = (int*)(small + 64);
  int*   tokexp  = (int*)(small + 256);
  float* tokgate = (float*)(small + 256 + ROWS * 2 * 4);
  int*   list    = (int*)(small + 256 + ROWS * 4 * 4);
  float* gate    = (float*)(small + 256 + ROWS * 4 * 4 + NENT * 4);

  hipMemsetAsync(cnt, 0, 128, stream);  // cnt + cursor
  k_ln<<<ROWS, 256, 0, stream>>>(tokA, tokC, tokB, ln1g, ln1b, xb);
  k_qkv_pack<<<384 + 1200, 256, 0, stream>>>(xb, Wqkv, bqkv, Qg, Kg, Vg,
                                             W1A, W1C, W1B, W2A, W2C, W2B, W1P, W2P);
  k_attn<<<dim3(32, 8, 4), 64, 0, stream>>>(Qg, Kg, Vg, attn);
  k_wo_pack<<<128 + 1200, 256, 0, stream>>>(attn, Wo, bo, tokA, tokC, tokB, out,
                                            W1A, W1C, W1B, W2A, W2C, W2B, W1P, W2P);
  k_router_pack<<<512 + 1184, 256, 0, stream>>>(out, ln2g, ln2b, WrA, brA, WrC, brC, WrB, brB,
                                                cnt, tokexp, tokgate, nrm,
                                                W1A, W1C, W1B, W2A, W2C, W2B, W1P, W2P);
  k_scatter<<<8, 256, 0, stream>>>(tokexp, tokgate, cnt, cursor, list, gate);
  k_moe1<<<dim3(16, 16, 14), 256, 0, stream>>>(nrm, W1P, b1A, b1C, b1B, cnt, list, H);
  k_moe2<<<dim3(4, 64, 14), 256, 0, stream>>>(H, W2P, b2A, b2C, b2B, cnt, list, gate, out);
}